// Round 1
// baseline (779.916 us; speedup 1.0000x reference)
//
#include <hip/hip_runtime.h>

// Problem constants
constexpr int Qn = 200;
constexpr int Nn = 25;
constexpr int Cn = 640;
constexpr int Hn = 5;
constexpr int Wn = 5;
constexpr int HWn = Hn * Wn;            // 25
constexpr int CHW = Cn * HWn;           // 16000
constexpr float TEMP_INV = 10.0f;       // 1 / 0.1
constexpr float EPSC = 1e-8f;

// -------------------------------------------------------------------------
// Kernel 1: per (q,n) tile, compute
//   m_s[p] = sum_c fs[c,p] * (sum_p' fq[c,p'])   (p = i*5+j support spatial)
//   m_q[p] = sum_c fq[c,p] * (sum_p' fs[c,p'])
// then row-wise (5-wide) softmax of m_s/25 -> s_att, of m_q/25 -> q_att,
// q_att accumulated into qbar[n] with 1/Q weight.
// -------------------------------------------------------------------------
__global__ __launch_bounds__(256) void attn_kernel(
    const float* __restrict__ fq, const float* __restrict__ fs,
    float* __restrict__ s_att, float* __restrict__ qbar)
{
    const int qn = blockIdx.x;          // 0 .. Q*N-1
    const int n  = qn % Nn;
    const float* fq_t = fq + (size_t)qn * CHW;
    const float* fs_t = fs + (size_t)qn * CHW;

    float ms[HWn], mq[HWn];
#pragma unroll
    for (int p = 0; p < HWn; ++p) { ms[p] = 0.f; mq[p] = 0.f; }

    const int tid = threadIdx.x;
    for (int c = tid; c < Cn; c += 256) {
        const float* fqr = fq_t + c * HWn;
        const float* fsr = fs_t + c * HWn;
        float vq[HWn], vs[HWn];
        float sq = 0.f, ss = 0.f;
#pragma unroll
        for (int p = 0; p < HWn; ++p) { vq[p] = fqr[p]; sq += vq[p]; }
#pragma unroll
        for (int p = 0; p < HWn; ++p) { vs[p] = fsr[p]; ss += vs[p]; }
#pragma unroll
        for (int p = 0; p < HWn; ++p) {
            ms[p] += vs[p] * sq;
            mq[p] += vq[p] * ss;
        }
    }

    // Reduce ms/mq across the workgroup: wave shuffle, then LDS across waves.
    __shared__ float red[4 * 2 * HWn];   // [wave][ms(25) | mq(25)]
    __shared__ float fm[2 * HWn];
    const int lane = tid & 63;
    const int wave = tid >> 6;
#pragma unroll
    for (int p = 0; p < HWn; ++p) {
        float v = ms[p];
        v += __shfl_down(v, 32); v += __shfl_down(v, 16); v += __shfl_down(v, 8);
        v += __shfl_down(v, 4);  v += __shfl_down(v, 2);  v += __shfl_down(v, 1);
        if (lane == 0) red[wave * (2 * HWn) + p] = v;
        float u = mq[p];
        u += __shfl_down(u, 32); u += __shfl_down(u, 16); u += __shfl_down(u, 8);
        u += __shfl_down(u, 4);  u += __shfl_down(u, 2);  u += __shfl_down(u, 1);
        if (lane == 0) red[wave * (2 * HWn) + HWn + p] = u;
    }
    __syncthreads();
    if (tid < 2 * HWn) {
        fm[tid] = red[tid] + red[2 * HWn + tid] + red[4 * HWn + tid] + red[6 * HWn + tid];
    }
    __syncthreads();

    // 10 rows of 5: rows 0..4 -> s_att, rows 5..9 -> q_att
    if (tid < 10) {
        const int r = tid;
        const float* row = (r < 5) ? &fm[r * 5] : &fm[HWn + (r - 5) * 5];
        float v[5];
        float mx = -1e30f;
#pragma unroll
        for (int j = 0; j < 5; ++j) {
            v[j] = row[j] * (1.0f / HWn);   // corr.mean over 25 opposite-spatial
            mx = fmaxf(mx, v[j]);
        }
        float s = 0.f;
#pragma unroll
        for (int j = 0; j < 5; ++j) { v[j] = __expf(v[j] - mx); s += v[j]; }
        const float inv = 1.0f / s;
        if (r < 5) {
#pragma unroll
            for (int j = 0; j < 5; ++j)
                s_att[(size_t)qn * HWn + r * 5 + j] = v[j] * inv;
        } else {
#pragma unroll
            for (int j = 0; j < 5; ++j)
                atomicAdd(&qbar[n * HWn + (r - 5) * 5 + j],
                          v[j] * inv * (1.0f / Qn));
        }
    }
}

// -------------------------------------------------------------------------
// Kernel 2: attended_s[n, c, hw] = (1/Q) * sum_q s_att[q,n,hw] * fs[q,n,c,hw]
// grid: (63, N); each thread owns one flat (c,hw) element of one n.
// -------------------------------------------------------------------------
__global__ __launch_bounds__(256) void agg_kernel(
    const float* __restrict__ fs, const float* __restrict__ s_att,
    float* __restrict__ att_s)
{
    const int n = blockIdx.y;
    const int f = blockIdx.x * 256 + threadIdx.x;   // 0 .. CHW-1
    if (f >= CHW) return;
    const int hw = f % HWn;
    float acc = 0.f;
    for (int q = 0; q < Qn; ++q) {
        const int qn = q * Nn + n;
        const float w = s_att[(size_t)qn * HWn + hw];
        acc += w * fs[(size_t)qn * CHW + f];
    }
    att_s[(size_t)n * CHW + f] = acc * (1.0f / Qn);
}

// -------------------------------------------------------------------------
// Kernel 3: out[q,n,c,h] = cosine_W(att_s[n,c,h,:], fq[q,n,c,h,:]*qbar[n,h,:])
//           / TEMPERATURE, with torch eps clamp on both norms.
// -------------------------------------------------------------------------
__global__ __launch_bounds__(256) void cos_kernel(
    const float* __restrict__ fq, const float* __restrict__ att_s,
    const float* __restrict__ qbar, float* __restrict__ out)
{
    const size_t idx = (size_t)blockIdx.x * 256 + threadIdx.x;  // over Q*N*C*H
    if (idx >= (size_t)Qn * Nn * Cn * Hn) return;
    const int h = (int)(idx % Hn);
    const size_t t = idx / Hn;
    const int c = (int)(t % Cn);
    const size_t qn = t / Cn;
    const int n = (int)(qn % Nn);

    const float* fqr = fq + (qn * Cn + c) * HWn + h * Wn;
    const float* asr = att_s + ((size_t)n * Cn + c) * HWn + h * Wn;
    const float* qb  = qbar + n * HWn + h * Wn;

    float dot = 0.f, ns2 = 0.f, nq2 = 0.f;
#pragma unroll
    for (int w = 0; w < Wn; ++w) {
        const float aq = fqr[w] * qb[w];
        const float as = asr[w];
        dot += as * aq;
        ns2 += as * as;
        nq2 += aq * aq;
    }
    const float ns = fmaxf(sqrtf(ns2), EPSC);
    const float nq = fmaxf(sqrtf(nq2), EPSC);
    out[idx] = dot / (ns * nq) * TEMP_INV;
}

// -------------------------------------------------------------------------
extern "C" void kernel_launch(void* const* d_in, const int* in_sizes, int n_in,
                              void* d_out, int out_size, void* d_ws, size_t ws_size,
                              hipStream_t stream)
{
    const float* fq = (const float*)d_in[0];   // feature_q [Q,N,C,H,W]
    const float* fs = (const float*)d_in[1];   // feature_s [Q,N,C,H,W]
    float* out = (float*)d_out;                // [Q,N,C,H]

    // Workspace layout (floats): s_att [Q*N*25] | qbar [N*25 (pad to 1024)] | att_s [N*C*25]
    float* s_att = (float*)d_ws;                          // 125000 floats
    float* qbar  = s_att + (size_t)Qn * Nn * HWn;         // 625 floats
    float* att_s = qbar + 1024;                           // 400000 floats

    hipMemsetAsync(qbar, 0, Nn * HWn * sizeof(float), stream);

    attn_kernel<<<Qn * Nn, 256, 0, stream>>>(fq, fs, s_att, qbar);

    dim3 g2((CHW + 255) / 256, Nn);
    agg_kernel<<<g2, 256, 0, stream>>>(fs, s_att, att_s);

    const size_t total = (size_t)Qn * Nn * Cn * Hn;
    cos_kernel<<<(unsigned)((total + 255) / 256), 256, 0, stream>>>(fq, att_s, qbar, out);
}

// Round 2
// 775.463 us; speedup vs baseline: 1.0057x; 1.0057x over previous
//
#include <hip/hip_runtime.h>

// Problem constants
constexpr int Qn = 200;
constexpr int Nn = 25;
constexpr int Cn = 640;
constexpr int Hn = 5;
constexpr int Wn = 5;
constexpr int HWn = Hn * Wn;            // 25
constexpr int CHW = Cn * HWn;           // 16000
constexpr float TEMP_INV = 10.0f;       // 1 / 0.1
constexpr float EPSC = 1e-8f;

typedef const float __attribute__((address_space(1)))* gbl_f;
typedef float __attribute__((address_space(3)))* lds_f;

__device__ __forceinline__ float wave_sum(float v) {
    v += __shfl_down(v, 32); v += __shfl_down(v, 16); v += __shfl_down(v, 8);
    v += __shfl_down(v, 4);  v += __shfl_down(v, 2);  v += __shfl_down(v, 1);
    return v;
}

// -------------------------------------------------------------------------
// Kernel 1: per (q,n) tile:
//   ms[p] = sum_c fs[c,p] * (sum_p' fq[c,p'])
//   mq[p] = sum_c fq[c,p] * (sum_p' fs[c,p'])
// row-softmax(ms/25) -> s_att ;  row-softmax(mq/25)/Q -> atomic into qbar[n].
// Staging: per-wave 64-channel tiles, global_load_lds width-16 (coalesced),
// then per-lane LDS row reads (stride 25 dwords: odd -> 2-way max, free).
// -------------------------------------------------------------------------
__global__ __launch_bounds__(256) void attn_kernel(
    const float* __restrict__ fq, const float* __restrict__ fs,
    float* __restrict__ s_att, float* __restrict__ qbar)
{
    // per-wave staging: [wave][fq 1600 | fs 1600] floats = 51200 B total
    __shared__ float lds[4 * 3200];

    const int qn   = blockIdx.x;          // 0 .. Q*N-1
    const int n    = qn % Nn;
    const int tid  = threadIdx.x;
    const int lane = tid & 63;
    const int wave = tid >> 6;

    const float* fq_t = fq + (size_t)qn * CHW;
    const float* fs_t = fs + (size_t)qn * CHW;
    float* ldsq = &lds[wave * 3200];
    float* ldss = ldsq + 1600;

    float ms[HWn], mq[HWn];
#pragma unroll
    for (int p = 0; p < HWn; ++p) { ms[p] = 0.f; mq[p] = 0.f; }

    // 10 channel-tiles of 64; wave w handles tiles w, w+4, w+8
    for (int tile = wave; tile < 10; tile += 4) {
        const float* gq = fq_t + tile * 1600;
        const float* gs = fs_t + tile * 1600;

        // drain previous tile's LDS reads before overwriting
        asm volatile("s_waitcnt lgkmcnt(0)" ::: "memory");

        // stage 1600 floats per array: 6 x (64 lanes x 16B) + 1 x (64 x 4B)
#pragma unroll
        for (int i = 0; i < 6; ++i) {
            __builtin_amdgcn_global_load_lds((gbl_f)(gq + (i * 64 + lane) * 4),
                                             (lds_f)(ldsq + i * 256), 16, 0, 0);
            __builtin_amdgcn_global_load_lds((gbl_f)(gs + (i * 64 + lane) * 4),
                                             (lds_f)(ldss + i * 256), 16, 0, 0);
        }
        __builtin_amdgcn_global_load_lds((gbl_f)(gq + 1536 + lane),
                                         (lds_f)(ldsq + 1536), 4, 0, 0);
        __builtin_amdgcn_global_load_lds((gbl_f)(gs + 1536 + lane),
                                         (lds_f)(ldss + 1536), 4, 0, 0);
        asm volatile("s_waitcnt vmcnt(0)" ::: "memory");

        // lane owns channel (tile*64 + lane): row of 25 in LDS
        const float* rq = ldsq + lane * HWn;
        const float* rs = ldss + lane * HWn;
        float vq[HWn], vs[HWn];
        float sq = 0.f, ssv = 0.f;
#pragma unroll
        for (int p = 0; p < HWn; ++p) { vq[p] = rq[p]; sq += vq[p]; }
#pragma unroll
        for (int p = 0; p < HWn; ++p) { vs[p] = rs[p]; ssv += vs[p]; }
#pragma unroll
        for (int p = 0; p < HWn; ++p) {
            ms[p] += vs[p] * sq;
            mq[p] += vq[p] * ssv;
        }
    }

    __syncthreads();   // staging LDS reused as reduction scratch below

    float* red = lds;                 // [wave][ms 25 | mq 25] -> 200 floats
    float* fm  = lds + 200;           // final [ms 25 | mq 25]
#pragma unroll
    for (int p = 0; p < HWn; ++p) {
        float v = wave_sum(ms[p]);
        if (lane == 0) red[wave * 50 + p] = v;
        float u = wave_sum(mq[p]);
        if (lane == 0) red[wave * 50 + HWn + p] = u;
    }
    __syncthreads();
    if (tid < 50) {
        fm[tid] = red[tid] + red[50 + tid] + red[100 + tid] + red[150 + tid];
    }
    __syncthreads();

    // 10 rows of 5: rows 0..4 -> s_att (support), rows 5..9 -> q_att -> qbar
    if (tid < 10) {
        const int r = tid;
        const float* row = (r < 5) ? &fm[r * 5] : &fm[HWn + (r - 5) * 5];
        float v[5];
        float mx = -1e30f;
#pragma unroll
        for (int j = 0; j < 5; ++j) {
            v[j] = row[j] * (1.0f / HWn);
            mx = fmaxf(mx, v[j]);
        }
        float s = 0.f;
#pragma unroll
        for (int j = 0; j < 5; ++j) { v[j] = __expf(v[j] - mx); s += v[j]; }
        const float inv = 1.0f / s;
        if (r < 5) {
#pragma unroll
            for (int j = 0; j < 5; ++j)
                s_att[(size_t)qn * HWn + r * 5 + j] = v[j] * inv;
        } else {
#pragma unroll
            for (int j = 0; j < 5; ++j)
                atomicAdd(&qbar[n * HWn + (r - 5) * 5 + j],
                          v[j] * inv * (1.0f / Qn));
        }
    }
}

// -------------------------------------------------------------------------
// Kernel 2: attended_s[n,c,hw] += (1/Q) * sum_{q in chunk} s_att[q,n,hw]*fs
// grid (16, N, 5): q split into 5 chunks of 40 for occupancy; float4 loads;
// s_att chunk staged in LDS; fp32 atomicAdd into zero-initialized att_s.
// -------------------------------------------------------------------------
__global__ __launch_bounds__(256) void agg_kernel(
    const float* __restrict__ fs, const float* __restrict__ s_att,
    float* __restrict__ att_s)
{
    constexpr int QCH = 40;
    __shared__ float w_lds[QCH * HWn];   // 1000 floats
    const int n  = blockIdx.y;
    const int q0 = blockIdx.z * QCH;

    for (int i = threadIdx.x; i < QCH * HWn; i += 256) {
        const int q = q0 + i / HWn;
        const int hw = i % HWn;
        w_lds[i] = s_att[(size_t)(q * Nn + n) * HWn + hw];
    }
    __syncthreads();

    const int f4 = blockIdx.x * 256 + threadIdx.x;   // float4 index, 0..3999
    if (f4 >= CHW / 4) return;
    const int f = f4 * 4;
    const int hw0 = f % HWn, hw1 = (f + 1) % HWn,
              hw2 = (f + 2) % HWn, hw3 = (f + 3) % HWn;

    float4 acc = make_float4(0.f, 0.f, 0.f, 0.f);
#pragma unroll 4
    for (int qi = 0; qi < QCH; ++qi) {
        const int q = q0 + qi;
        const float4 v = *(const float4*)(fs + (size_t)(q * Nn + n) * CHW + f);
        const float* w = &w_lds[qi * HWn];
        acc.x += w[hw0] * v.x;
        acc.y += w[hw1] * v.y;
        acc.z += w[hw2] * v.z;
        acc.w += w[hw3] * v.w;
    }
    float* dst = att_s + (size_t)n * CHW + f;
    atomicAdd(dst + 0, acc.x * (1.0f / Qn));
    atomicAdd(dst + 1, acc.y * (1.0f / Qn));
    atomicAdd(dst + 2, acc.z * (1.0f / Qn));
    atomicAdd(dst + 3, acc.w * (1.0f / Qn));
}

// -------------------------------------------------------------------------
// Kernel 3: out[q,n,c,h] = cos_W(att_s[n,c,h,:], fq[q,n,c,h,:]*qbar[n,h,:]) * 10
// -------------------------------------------------------------------------
__global__ __launch_bounds__(256) void cos_kernel(
    const float* __restrict__ fq, const float* __restrict__ att_s,
    const float* __restrict__ qbar, float* __restrict__ out)
{
    const size_t idx = (size_t)blockIdx.x * 256 + threadIdx.x;  // over Q*N*C*H
    if (idx >= (size_t)Qn * Nn * Cn * Hn) return;
    const int h = (int)(idx % Hn);
    const size_t t = idx / Hn;
    const int c = (int)(t % Cn);
    const size_t qn = t / Cn;
    const int n = (int)(qn % Nn);

    const float* fqr = fq + (qn * Cn + c) * HWn + h * Wn;
    const float* asr = att_s + ((size_t)n * Cn + c) * HWn + h * Wn;
    const float* qb  = qbar + n * HWn + h * Wn;

    float dot = 0.f, ns2 = 0.f, nq2 = 0.f;
#pragma unroll
    for (int w = 0; w < Wn; ++w) {
        const float aq = fqr[w] * qb[w];
        const float as = asr[w];
        dot += as * aq;
        ns2 += as * as;
        nq2 += aq * aq;
    }
    const float ns = fmaxf(sqrtf(ns2), EPSC);
    const float nq = fmaxf(sqrtf(nq2), EPSC);
    out[idx] = dot / (ns * nq) * TEMP_INV;
}

// -------------------------------------------------------------------------
extern "C" void kernel_launch(void* const* d_in, const int* in_sizes, int n_in,
                              void* d_out, int out_size, void* d_ws, size_t ws_size,
                              hipStream_t stream)
{
    const float* fq = (const float*)d_in[0];   // feature_q [Q,N,C,H,W]
    const float* fs = (const float*)d_in[1];   // feature_s [Q,N,C,H,W]
    float* out = (float*)d_out;                // [Q,N,C,H]

    // Workspace (floats): s_att [Q*N*25] | qbar [25*25 pad->1024] | att_s [N*C*25]
    float* s_att = (float*)d_ws;                          // 125000 floats
    float* qbar  = s_att + (size_t)Qn * Nn * HWn;         // 625 floats (pad 1024)
    float* att_s = qbar + 1024;                           // 400000 floats

    // zero qbar + pad + att_s in one async memset
    hipMemsetAsync(qbar, 0, (1024 + (size_t)Nn * CHW) * sizeof(float), stream);

    attn_kernel<<<Qn * Nn, 256, 0, stream>>>(fq, fs, s_att, qbar);

    dim3 g2((CHW / 4 + 255) / 256, Nn, 5);
    agg_kernel<<<g2, 256, 0, stream>>>(fs, s_att, att_s);

    const size_t total = (size_t)Qn * Nn * Cn * Hn;
    cos_kernel<<<(unsigned)((total + 255) / 256), 256, 0, stream>>>(fq, att_s, qbar, out);
}